// Round 5
// baseline (123.938 us; speedup 1.0000x reference)
//
#include <hip/hip_runtime.h>

// QCQP quaternion loss. Per element: smallest eigenpair of 4x4 symmetric A
// via characteristic polynomial + monotone Newton from Gershgorin lower
// bound; eigenvector = 4D cross of 3 rows of A-lam*I (max-norm candidate);
// loss = 8(1 - <v,qt>^2/|v|^2). Mean-reduce with fused finalize.
//
// R4: R1-R3 were all L1/TA transaction-bound (VALUBusy*dur ~= const 9-10us,
// HBM 5%, LDS 0): the 40B-strided float2 AoS loads touch ~20 cache lines
// per wave-instruction. Fix: coalesced LDS staging (5 contiguous float2
// rounds per block), per-thread reads from LDS. Compute = proven R1 path.

#define TPB 256

__device__ __forceinline__ void cross4(const float* x, const float* y,
                                       const float* z, float* w) {
    float m01 = y[0]*z[1] - y[1]*z[0];
    float m02 = y[0]*z[2] - y[2]*z[0];
    float m03 = y[0]*z[3] - y[3]*z[0];
    float m12 = y[1]*z[2] - y[2]*z[1];
    float m13 = y[1]*z[3] - y[3]*z[1];
    float m23 = y[2]*z[3] - y[3]*z[2];
    w[0] =  (x[1]*m23 - x[2]*m13 + x[3]*m12);
    w[1] = -(x[0]*m23 - x[2]*m03 + x[3]*m02);
    w[2] =  (x[0]*m13 - x[1]*m03 + x[3]*m01);
    w[3] = -(x[0]*m12 - x[1]*m02 + x[2]*m01);
}

__device__ __forceinline__ float det3s(float p, float q, float r,
                                       float s, float t, float u) {
    return p*(s*u - t*t) - q*(q*u - r*t) + r*(q*t - r*s);
}

__global__ __launch_bounds__(TPB) void qcqp_loss_kernel(
    const float* __restrict__ A_vec, const float* __restrict__ q_t,
    float* __restrict__ acc, unsigned int* __restrict__ cnt,
    float* __restrict__ out, int B, int nblocks)
{
    __shared__ float sA[TPB * 10];
    int t = threadIdx.x;
    size_t eb = (size_t)blockIdx.x * TPB;      // first element of this block

    // ---- coalesced staging: block's A slice = TPB*10 floats = TPB*5 float2
    const float2* src = (const float2*)A_vec;
    size_t pairBase = eb * 5;
    size_t totalPairs = (size_t)B * 5;
    #pragma unroll
    for (int r = 0; r < 5; ++r) {
        size_t L = pairBase + (size_t)(r * TPB + t);
        float2 v = (L < totalPairs) ? src[L] : make_float2(0.f, 0.f);
        int l = r * TPB + t;                   // linear in lane -> no conflict
        sA[2*l]   = v.x;
        sA[2*l+1] = v.y;
    }
    __syncthreads();

    int i = (int)eb + t;
    bool act = (i < B);
    float lsum = 0.f;
    {
        const float* a = &sA[t * 10];          // ds_read_b64 x5, 4-way conf
        float m00 = -a[0], m01 = -a[1], m02 = -a[2], m03 = -a[3];
        float m11 = -a[4], m12 = -a[5], m13 = -a[6];
        float m22 = -a[7], m23 = -a[8], m33 = -a[9];

        // characteristic polynomial l^4 - e1 l^3 + e2 l^2 - e3 l + e4
        float e1 = m00 + m11 + m22 + m33;
        float e2 = m00*m11 - m01*m01 + m00*m22 - m02*m02 + m00*m33 - m03*m03
                 + m11*m22 - m12*m12 + m11*m33 - m13*m13 + m22*m33 - m23*m23;
        float e3 = det3s(m11, m12, m13, m22, m23, m33)
                 + det3s(m00, m02, m03, m22, m23, m33)
                 + det3s(m00, m01, m03, m11, m13, m33)
                 + det3s(m00, m01, m02, m11, m12, m22);
        float r1v[4] = {m01, m11, m12, m13};
        float r2v[4] = {m02, m12, m22, m23};
        float r3v[4] = {m03, m13, m23, m33};
        float cw[4];
        cross4(r1v, r2v, r3v, cw);
        float e4 = m00*cw[0] + m01*cw[1] + m02*cw[2] + m03*cw[3];

        // Gershgorin bracket, Newton from below (monotone)
        float s0 = fabsf(m01) + fabsf(m02) + fabsf(m03);
        float s1 = fabsf(m01) + fabsf(m12) + fabsf(m13);
        float s2 = fabsf(m02) + fabsf(m12) + fabsf(m23);
        float s3 = fabsf(m03) + fabsf(m13) + fabsf(m23);
        float lo = fminf(fminf(m00 - s0, m11 - s1), fminf(m22 - s2, m33 - s3)) - 1e-3f;
        float hi = fminf(fminf(m00, m11), fminf(m22, m33));
        float lam = lo;
        #pragma unroll
        for (int it = 0; it < 12; ++it) {
            float p  = (((lam - e1)*lam + e2)*lam - e3)*lam + e4;
            float dp = ((4.f*lam - 3.f*e1)*lam + 2.f*e2)*lam - e3;
            dp = fminf(dp, -1e-12f);
            lam = lam - p * __builtin_amdgcn_rcpf(dp);
            lam = fminf(fmaxf(lam, lo), hi);
        }

        // eigenvector = max-norm 4D cross of rows of A - lam I
        float R0[4] = {m00 - lam, m01, m02, m03};
        float R1[4] = {m01, m11 - lam, m12, m13};
        float R2[4] = {m02, m12, m22 - lam, m23};
        float R3[4] = {m03, m13, m23, m33 - lam};
        float c0[4], c1[4], c2[4], c3[4];
        cross4(R1, R2, R3, c0);
        cross4(R0, R2, R3, c1);
        cross4(R0, R1, R3, c2);
        cross4(R0, R1, R2, c3);
        float n0 = c0[0]*c0[0] + c0[1]*c0[1] + c0[2]*c0[2] + c0[3]*c0[3];
        float n1 = c1[0]*c1[0] + c1[1]*c1[1] + c1[2]*c1[2] + c1[3]*c1[3];
        float n2 = c2[0]*c2[0] + c2[1]*c2[1] + c2[2]*c2[2] + c2[3]*c2[3];
        float n3 = c3[0]*c3[0] + c3[1]*c3[1] + c3[2]*c3[2] + c3[3]*c3[3];

        float bn = n0, w0 = c0[0], w1 = c0[1], w2 = c0[2], w3 = c0[3];
        bool b;
        b = n1 > bn; bn = b ? n1 : bn; w0 = b ? c1[0] : w0; w1 = b ? c1[1] : w1;
                     w2 = b ? c1[2] : w2; w3 = b ? c1[3] : w3;
        b = n2 > bn; bn = b ? n2 : bn; w0 = b ? c2[0] : w0; w1 = b ? c2[1] : w1;
                     w2 = b ? c2[2] : w2; w3 = b ? c2[3] : w3;
        b = n3 > bn; bn = b ? n3 : bn; w0 = b ? c3[0] : w0; w1 = b ? c3[1] : w1;
                     w2 = b ? c3[2] : w2; w3 = b ? c3[3] : w3;

        // loss (q_t load is already coalesced: 16B/lane)
        float4 qt = *(const float4*)(q_t + (size_t)(act ? i : 0) * 4);
        float d = w0*qt.x + w1*qt.y + w2*qt.z + w3*qt.w;
        float inv = __builtin_amdgcn_rcpf(fmaxf(bn, 1e-20f));
        float loss = 8.f * (bn - d*d) * inv;
        loss = fminf(fmaxf(loss, 0.f), 8.f);
        lsum = act ? loss : 0.f;
    }

    // ---- block reduction: wave64 shuffle -> LDS -> one atomic per block ---
    #pragma unroll
    for (int off = 32; off > 0; off >>= 1)
        lsum += __shfl_down(lsum, off, 64);
    __shared__ float sm[4];
    int lane = threadIdx.x & 63, wid = threadIdx.x >> 6;
    if (lane == 0) sm[wid] = lsum;
    __syncthreads();
    if (threadIdx.x == 0) {
        atomicAdd(acc, sm[0] + sm[1] + sm[2] + sm[3]);
        __threadfence();
        unsigned int c = atomicAdd(cnt, 1u);
        if (c == (unsigned int)(nblocks - 1)) {
            float total = atomicAdd(acc, 0.f);
            out[0] = total / (float)B;
        }
    }
}

extern "C" void kernel_launch(void* const* d_in, const int* in_sizes, int n_in,
                              void* d_out, int out_size, void* d_ws, size_t ws_size,
                              hipStream_t stream)
{
    const float* A_vec = (const float*)d_in[0];
    const float* q_t   = (const float*)d_in[1];
    int B = in_sizes[0] / 10;
    float* acc = (float*)d_ws;
    unsigned int* cnt = (unsigned int*)((char*)d_ws + sizeof(float));

    hipMemsetAsync(d_ws, 0, 2 * sizeof(float), stream);
    int nblocks = (B + TPB - 1) / TPB;
    qcqp_loss_kernel<<<nblocks, TPB, 0, stream>>>(
        A_vec, q_t, acc, cnt, (float*)d_out, B, nblocks);
}

// Round 7
// 82.416 us; speedup vs baseline: 1.5038x; 1.5038x over previous
//
#include <hip/hip_runtime.h>

// QCQP quaternion loss. Per element: smallest eigenpair of 4x4 symmetric A
// via characteristic polynomial + monotone Newton from Gershgorin lower
// bound; eigenvector = 4D cross of 3 rows of A-lam*I (max-norm candidate);
// loss = 8(1 - <v,qt>^2/|v|^2). Mean-reduce with fused finalize.
//
// R5 model (from R1/R2/R4 fits): duration ~ total memory-pipe instruction
// count (global + LDS-pipe), not coalescing. So: (a) pair-packed float4
// loads -> 3.5 mem-instrs/element instead of 6; (b) wave reduction via DPP
// (VALU pipe) instead of __shfl (LDS pipe); (c) math identical to R1.
// R6: fix compile error -- update_dpp ctrl/mask must be template constants.

#define TPB 256

__device__ __forceinline__ void cross4(const float* x, const float* y,
                                       const float* z, float* w) {
    float m01 = y[0]*z[1] - y[1]*z[0];
    float m02 = y[0]*z[2] - y[2]*z[0];
    float m03 = y[0]*z[3] - y[3]*z[0];
    float m12 = y[1]*z[2] - y[2]*z[1];
    float m13 = y[1]*z[3] - y[3]*z[1];
    float m23 = y[2]*z[3] - y[3]*z[2];
    w[0] =  (x[1]*m23 - x[2]*m13 + x[3]*m12);
    w[1] = -(x[0]*m23 - x[2]*m03 + x[3]*m02);
    w[2] =  (x[0]*m13 - x[1]*m03 + x[3]*m01);
    w[3] = -(x[0]*m12 - x[1]*m02 + x[2]*m01);
}

__device__ __forceinline__ float det3s(float p, float q, float r,
                                       float s, float t, float u) {
    return p*(s*u - t*t) - q*(q*u - r*t) + r*(q*t - r*s);
}

// ---- R1's proven per-element solve (identical math) ----
__device__ __forceinline__ float solve_elem(const float a[10], float4 qt) {
    float m00 = -a[0], m01 = -a[1], m02 = -a[2], m03 = -a[3];
    float m11 = -a[4], m12 = -a[5], m13 = -a[6];
    float m22 = -a[7], m23 = -a[8], m33 = -a[9];

    float e1 = m00 + m11 + m22 + m33;
    float e2 = m00*m11 - m01*m01 + m00*m22 - m02*m02 + m00*m33 - m03*m03
             + m11*m22 - m12*m12 + m11*m33 - m13*m13 + m22*m33 - m23*m23;
    float e3 = det3s(m11, m12, m13, m22, m23, m33)
             + det3s(m00, m02, m03, m22, m23, m33)
             + det3s(m00, m01, m03, m11, m13, m33)
             + det3s(m00, m01, m02, m11, m12, m22);
    float r1v[4] = {m01, m11, m12, m13};
    float r2v[4] = {m02, m12, m22, m23};
    float r3v[4] = {m03, m13, m23, m33};
    float cw[4];
    cross4(r1v, r2v, r3v, cw);
    float e4 = m00*cw[0] + m01*cw[1] + m02*cw[2] + m03*cw[3];

    float s0 = fabsf(m01) + fabsf(m02) + fabsf(m03);
    float s1 = fabsf(m01) + fabsf(m12) + fabsf(m13);
    float s2 = fabsf(m02) + fabsf(m12) + fabsf(m23);
    float s3 = fabsf(m03) + fabsf(m13) + fabsf(m23);
    float lo = fminf(fminf(m00 - s0, m11 - s1), fminf(m22 - s2, m33 - s3)) - 1e-3f;
    float hi = fminf(fminf(m00, m11), fminf(m22, m33));
    float lam = lo;
    #pragma unroll
    for (int it = 0; it < 12; ++it) {
        float p  = (((lam - e1)*lam + e2)*lam - e3)*lam + e4;
        float dp = ((4.f*lam - 3.f*e1)*lam + 2.f*e2)*lam - e3;
        dp = fminf(dp, -1e-12f);
        lam = lam - p * __builtin_amdgcn_rcpf(dp);
        lam = fminf(fmaxf(lam, lo), hi);
    }

    float R0[4] = {m00 - lam, m01, m02, m03};
    float R1[4] = {m01, m11 - lam, m12, m13};
    float R2[4] = {m02, m12, m22 - lam, m23};
    float R3[4] = {m03, m13, m23, m33 - lam};
    float c0[4], c1[4], c2[4], c3[4];
    cross4(R1, R2, R3, c0);
    cross4(R0, R2, R3, c1);
    cross4(R0, R1, R3, c2);
    cross4(R0, R1, R2, c3);
    float n0 = c0[0]*c0[0] + c0[1]*c0[1] + c0[2]*c0[2] + c0[3]*c0[3];
    float n1 = c1[0]*c1[0] + c1[1]*c1[1] + c1[2]*c1[2] + c1[3]*c1[3];
    float n2 = c2[0]*c2[0] + c2[1]*c2[1] + c2[2]*c2[2] + c2[3]*c2[3];
    float n3 = c3[0]*c3[0] + c3[1]*c3[1] + c3[2]*c3[2] + c3[3]*c3[3];

    float bn = n0, w0 = c0[0], w1 = c0[1], w2 = c0[2], w3 = c0[3];
    bool b;
    b = n1 > bn; bn = b ? n1 : bn; w0 = b ? c1[0] : w0; w1 = b ? c1[1] : w1;
                 w2 = b ? c1[2] : w2; w3 = b ? c1[3] : w3;
    b = n2 > bn; bn = b ? n2 : bn; w0 = b ? c2[0] : w0; w1 = b ? c2[1] : w1;
                 w2 = b ? c2[2] : w2; w3 = b ? c2[3] : w3;
    b = n3 > bn; bn = b ? n3 : bn; w0 = b ? c3[0] : w0; w1 = b ? c3[1] : w1;
                 w2 = b ? c3[2] : w2; w3 = b ? c3[3] : w3;

    float d = w0*qt.x + w1*qt.y + w2*qt.z + w3*qt.w;
    float inv = __builtin_amdgcn_rcpf(fmaxf(bn, 1e-20f));
    float loss = 8.f * (bn - d*d) * inv;
    return fminf(fmaxf(loss, 0.f), 8.f);
}

// DPP wave64 sum step: VALU pipe only. ctrl/mask are compile-time consts.
template <int CTRL, int ROW_MASK>
__device__ __forceinline__ float dpp_add(float v) {
    int t = __builtin_amdgcn_update_dpp(0, __builtin_bit_cast(int, v),
                                        CTRL, ROW_MASK, 0xf, true);
    return v + __builtin_bit_cast(float, t);
}

__global__ __launch_bounds__(TPB, 2) void qcqp_loss_kernel(
    const float* __restrict__ A_vec, const float* __restrict__ q_t,
    float* __restrict__ acc, unsigned int* __restrict__ cnt,
    float* __restrict__ out, int B, int nthreads, int nblocks)
{
    int t = blockIdx.x * blockDim.x + threadIdx.x;
    float lsum = 0.f;

    if (t < nthreads) {
        int i0 = 2 * t, i1 = 2 * t + 1;
        if (i1 < B) {
            // ---- pair path: 5x float4 (A pair) + 2x float4 (qt) ----
            const float4* f = (const float4*)(A_vec) + (size_t)5 * t;
            float4 f0 = f[0], f1 = f[1], f2 = f[2], f3 = f[3], f4v = f[4];
            const float4* qf = (const float4*)q_t;
            float4 qt0 = qf[i0], qt1 = qf[i1];

            float a0[10] = {f0.x, f0.y, f0.z, f0.w, f1.x, f1.y, f1.z, f1.w,
                            f2.x, f2.y};
            float a1[10] = {f2.z, f2.w, f3.x, f3.y, f3.z, f3.w, f4v.x, f4v.y,
                            f4v.z, f4v.w};
            lsum = solve_elem(a0, qt0) + solve_elem(a1, qt1);
        } else if (i0 < B) {
            // ---- odd-B tail: single element via float2 loads ----
            const float* av = A_vec + (size_t)i0 * 10;
            float2 v01 = *(const float2*)(av + 0);
            float2 v23 = *(const float2*)(av + 2);
            float2 v45 = *(const float2*)(av + 4);
            float2 v67 = *(const float2*)(av + 6);
            float2 v89 = *(const float2*)(av + 8);
            float a0[10] = {v01.x, v01.y, v23.x, v23.y, v45.x,
                            v45.y, v67.x, v67.y, v89.x, v89.y};
            float4 qt0 = *(const float4*)(q_t + (size_t)i0 * 4);
            lsum = solve_elem(a0, qt0);
        }
    }

    // ---- wave64 sum on the VALU pipe (DPP), total lands in lane 63 ----
    lsum = dpp_add<0x111, 0xf>(lsum);   // row_shr:1
    lsum = dpp_add<0x112, 0xf>(lsum);   // row_shr:2
    lsum = dpp_add<0x114, 0xf>(lsum);   // row_shr:4
    lsum = dpp_add<0x118, 0xf>(lsum);   // row_shr:8
    lsum = dpp_add<0x142, 0xa>(lsum);   // row_bcast:15 -> rows 1,3
    lsum = dpp_add<0x143, 0xc>(lsum);   // row_bcast:31 -> rows 2,3
    float wsum = __builtin_bit_cast(float,
        __builtin_amdgcn_readlane(__builtin_bit_cast(int, lsum), 63));

    __shared__ float sm[TPB / 64];
    int lane = threadIdx.x & 63, wid = threadIdx.x >> 6;
    if (lane == 0) sm[wid] = wsum;
    __syncthreads();
    if (threadIdx.x == 0) {
        float bsum = sm[0] + sm[1] + sm[2] + sm[3];
        atomicAdd(acc, bsum);
        __threadfence();
        unsigned int c = atomicAdd(cnt, 1u);
        if (c == (unsigned int)(nblocks - 1)) {
            float total = atomicAdd(acc, 0.f);
            out[0] = total / (float)B;
        }
    }
}

extern "C" void kernel_launch(void* const* d_in, const int* in_sizes, int n_in,
                              void* d_out, int out_size, void* d_ws, size_t ws_size,
                              hipStream_t stream)
{
    const float* A_vec = (const float*)d_in[0];
    const float* q_t   = (const float*)d_in[1];
    int B = in_sizes[0] / 10;
    float* acc = (float*)d_ws;
    unsigned int* cnt = (unsigned int*)((char*)d_ws + sizeof(float));

    (void)hipMemsetAsync(d_ws, 0, 2 * sizeof(float), stream);
    int nthreads = (B + 1) / 2;
    int nblocks = (nthreads + TPB - 1) / TPB;
    qcqp_loss_kernel<<<nblocks, TPB, 0, stream>>>(
        A_vec, q_t, acc, cnt, (float*)d_out, B, nthreads, nblocks);
}

// Round 8
// 48.409 us; speedup vs baseline: 2.5602x; 1.7025x over previous
//
#include <hip/hip_runtime.h>

// QCQP quaternion loss. Per element: smallest eigenpair of 4x4 symmetric A
// via characteristic polynomial + monotone Newton from Gershgorin lower
// bound; eigenvector = 4D cross of 3 rows of A-lam*I (max-norm candidate);
// loss = 8(1 - <v,qt>^2/|v|^2). Mean-reduce with fused finalize.
//
// R7: software pipeline. R1 (clean, no spill) stalls 48us on one exposed
// load latency per wave (issue 6 loads -> wait -> 700cy compute -> retire).
// Fix: 4 elements/thread sequentially, prefetching element k+1's 6 loads
// into registers BEFORE solving element k -> latency hides under the solve's
// VALU work within the same wave. State ~48 floats (prefetch 14 + live 20
// + temps) -- small enough to avoid the R2/R3/R6 spill trap. Math = R1.

#define TPB 256
#define ELEMS 4

__device__ __forceinline__ void cross4(const float* x, const float* y,
                                       const float* z, float* w) {
    float m01 = y[0]*z[1] - y[1]*z[0];
    float m02 = y[0]*z[2] - y[2]*z[0];
    float m03 = y[0]*z[3] - y[3]*z[0];
    float m12 = y[1]*z[2] - y[2]*z[1];
    float m13 = y[1]*z[3] - y[3]*z[1];
    float m23 = y[2]*z[3] - y[3]*z[2];
    w[0] =  (x[1]*m23 - x[2]*m13 + x[3]*m12);
    w[1] = -(x[0]*m23 - x[2]*m03 + x[3]*m02);
    w[2] =  (x[0]*m13 - x[1]*m03 + x[3]*m01);
    w[3] = -(x[0]*m12 - x[1]*m02 + x[2]*m01);
}

__device__ __forceinline__ float det3s(float p, float q, float r,
                                       float s, float t, float u) {
    return p*(s*u - t*t) - q*(q*u - r*t) + r*(q*t - r*s);
}

// ---- R1's proven per-element solve (identical math) ----
__device__ __forceinline__ float solve_elem(const float a[10], float4 qt) {
    float m00 = -a[0], m01 = -a[1], m02 = -a[2], m03 = -a[3];
    float m11 = -a[4], m12 = -a[5], m13 = -a[6];
    float m22 = -a[7], m23 = -a[8], m33 = -a[9];

    float e1 = m00 + m11 + m22 + m33;
    float e2 = m00*m11 - m01*m01 + m00*m22 - m02*m02 + m00*m33 - m03*m03
             + m11*m22 - m12*m12 + m11*m33 - m13*m13 + m22*m33 - m23*m23;
    float e3 = det3s(m11, m12, m13, m22, m23, m33)
             + det3s(m00, m02, m03, m22, m23, m33)
             + det3s(m00, m01, m03, m11, m13, m33)
             + det3s(m00, m01, m02, m11, m12, m22);
    float r1v[4] = {m01, m11, m12, m13};
    float r2v[4] = {m02, m12, m22, m23};
    float r3v[4] = {m03, m13, m23, m33};
    float cw[4];
    cross4(r1v, r2v, r3v, cw);
    float e4 = m00*cw[0] + m01*cw[1] + m02*cw[2] + m03*cw[3];

    float s0 = fabsf(m01) + fabsf(m02) + fabsf(m03);
    float s1 = fabsf(m01) + fabsf(m12) + fabsf(m13);
    float s2 = fabsf(m02) + fabsf(m12) + fabsf(m23);
    float s3 = fabsf(m03) + fabsf(m13) + fabsf(m23);
    float lo = fminf(fminf(m00 - s0, m11 - s1), fminf(m22 - s2, m33 - s3)) - 1e-3f;
    float hi = fminf(fminf(m00, m11), fminf(m22, m33));
    float lam = lo;
    #pragma unroll
    for (int it = 0; it < 12; ++it) {
        float p  = (((lam - e1)*lam + e2)*lam - e3)*lam + e4;
        float dp = ((4.f*lam - 3.f*e1)*lam + 2.f*e2)*lam - e3;
        dp = fminf(dp, -1e-12f);
        lam = lam - p * __builtin_amdgcn_rcpf(dp);
        lam = fminf(fmaxf(lam, lo), hi);
    }

    float R0[4] = {m00 - lam, m01, m02, m03};
    float R1[4] = {m01, m11 - lam, m12, m13};
    float R2[4] = {m02, m12, m22 - lam, m23};
    float R3[4] = {m03, m13, m23, m33 - lam};
    float c0[4], c1[4], c2[4], c3[4];
    cross4(R1, R2, R3, c0);
    cross4(R0, R2, R3, c1);
    cross4(R0, R1, R3, c2);
    cross4(R0, R1, R2, c3);
    float n0 = c0[0]*c0[0] + c0[1]*c0[1] + c0[2]*c0[2] + c0[3]*c0[3];
    float n1 = c1[0]*c1[0] + c1[1]*c1[1] + c1[2]*c1[2] + c1[3]*c1[3];
    float n2 = c2[0]*c2[0] + c2[1]*c2[1] + c2[2]*c2[2] + c2[3]*c2[3];
    float n3 = c3[0]*c3[0] + c3[1]*c3[1] + c3[2]*c3[2] + c3[3]*c3[3];

    float bn = n0, w0 = c0[0], w1 = c0[1], w2 = c0[2], w3 = c0[3];
    bool b;
    b = n1 > bn; bn = b ? n1 : bn; w0 = b ? c1[0] : w0; w1 = b ? c1[1] : w1;
                 w2 = b ? c1[2] : w2; w3 = b ? c1[3] : w3;
    b = n2 > bn; bn = b ? n2 : bn; w0 = b ? c2[0] : w0; w1 = b ? c2[1] : w1;
                 w2 = b ? c2[2] : w2; w3 = b ? c2[3] : w3;
    b = n3 > bn; bn = b ? n3 : bn; w0 = b ? c3[0] : w0; w1 = b ? c3[1] : w1;
                 w2 = b ? c3[2] : w2; w3 = b ? c3[3] : w3;

    float d = w0*qt.x + w1*qt.y + w2*qt.z + w3*qt.w;
    float inv = __builtin_amdgcn_rcpf(fmaxf(bn, 1e-20f));
    float loss = 8.f * (bn - d*d) * inv;
    return fminf(fmaxf(loss, 0.f), 8.f);
}

// DPP wave64 sum step: VALU pipe only. ctrl/mask are compile-time consts.
template <int CTRL, int ROW_MASK>
__device__ __forceinline__ float dpp_add(float v) {
    int t = __builtin_amdgcn_update_dpp(0, __builtin_bit_cast(int, v),
                                        CTRL, ROW_MASK, 0xf, true);
    return v + __builtin_bit_cast(float, t);
}

__global__ __launch_bounds__(TPB) void qcqp_loss_kernel(
    const float* __restrict__ A_vec, const float* __restrict__ q_t,
    float* __restrict__ acc, unsigned int* __restrict__ cnt,
    float* __restrict__ out, int B, int T, int nblocks)
{
    int tid = blockIdx.x * blockDim.x + threadIdx.x;
    float lsum = 0.f;

    // ---- prefetch element 0 ----
    int i = tid;
    bool act = (i < B);
    const float* av = A_vec + (size_t)(act ? i : 0) * 10;
    float2 p0 = *(const float2*)(av + 0);
    float2 p1 = *(const float2*)(av + 2);
    float2 p2 = *(const float2*)(av + 4);
    float2 p3 = *(const float2*)(av + 6);
    float2 p4 = *(const float2*)(av + 8);
    float4 pq = *(const float4*)(q_t + (size_t)(act ? i : 0) * 4);

    #pragma unroll
    for (int k = 0; k < ELEMS; ++k) {
        // current element's data (register rename from prefetch)
        float a[10] = {p0.x, p0.y, p1.x, p1.y, p2.x,
                       p2.y, p3.x, p3.y, p4.x, p4.y};
        float4 qt = pq;
        bool cur_act = act;

        // issue NEXT element's loads before the solve (latency hides under it)
        if (k + 1 < ELEMS) {
            int j = tid + (k + 1) * T;
            act = (j < B);
            const float* nav = A_vec + (size_t)(act ? j : 0) * 10;
            p0 = *(const float2*)(nav + 0);
            p1 = *(const float2*)(nav + 2);
            p2 = *(const float2*)(nav + 4);
            p3 = *(const float2*)(nav + 6);
            p4 = *(const float2*)(nav + 8);
            pq = *(const float4*)(q_t + (size_t)(act ? j : 0) * 4);
        }

        float loss = solve_elem(a, qt);
        lsum += cur_act ? loss : 0.f;
    }

    // ---- wave64 sum on the VALU pipe (DPP), total lands in lane 63 ----
    lsum = dpp_add<0x111, 0xf>(lsum);   // row_shr:1
    lsum = dpp_add<0x112, 0xf>(lsum);   // row_shr:2
    lsum = dpp_add<0x114, 0xf>(lsum);   // row_shr:4
    lsum = dpp_add<0x118, 0xf>(lsum);   // row_shr:8
    lsum = dpp_add<0x142, 0xa>(lsum);   // row_bcast:15 -> rows 1,3
    lsum = dpp_add<0x143, 0xc>(lsum);   // row_bcast:31 -> rows 2,3
    float wsum = __builtin_bit_cast(float,
        __builtin_amdgcn_readlane(__builtin_bit_cast(int, lsum), 63));

    __shared__ float sm[TPB / 64];
    int lane = threadIdx.x & 63, wid = threadIdx.x >> 6;
    if (lane == 0) sm[wid] = wsum;
    __syncthreads();
    if (threadIdx.x == 0) {
        float bsum = sm[0] + sm[1] + sm[2] + sm[3];
        atomicAdd(acc, bsum);
        __threadfence();
        unsigned int c = atomicAdd(cnt, 1u);
        if (c == (unsigned int)(nblocks - 1)) {
            float total = atomicAdd(acc, 0.f);
            out[0] = total / (float)B;
        }
    }
}

extern "C" void kernel_launch(void* const* d_in, const int* in_sizes, int n_in,
                              void* d_out, int out_size, void* d_ws, size_t ws_size,
                              hipStream_t stream)
{
    const float* A_vec = (const float*)d_in[0];
    const float* q_t   = (const float*)d_in[1];
    int B = in_sizes[0] / 10;
    float* acc = (float*)d_ws;
    unsigned int* cnt = (unsigned int*)((char*)d_ws + sizeof(float));

    (void)hipMemsetAsync(d_ws, 0, 2 * sizeof(float), stream);
    int T = (B + ELEMS - 1) / ELEMS;       // threads; elem idx = tid + k*T
    int nblocks = (T + TPB - 1) / TPB;
    qcqp_loss_kernel<<<nblocks, TPB, 0, stream>>>(
        A_vec, q_t, acc, cnt, (float*)d_out, B, T, nblocks);
}

// Round 9
// 35.492 us; speedup vs baseline: 3.4921x; 1.3640x over previous
//
#include <hip/hip_runtime.h>

// QCQP quaternion loss. Per element: smallest eigenpair of 4x4 symmetric A
// via characteristic polynomial + monotone Newton from Gershgorin lower
// bound; eigenvector = 4D cross of 3 rows of A-lam*I (max-norm candidate);
// loss = 8(1 - <v,qt>^2/|v|^2). Mean-reduce with fused finalize.
//
// R8: HARD-PINNED software pipeline (hipcc sank R7's source-level prefetch:
// VGPR stayed 32, time stayed ~55us). Loads issued via asm volatile
// global_load_dwordx4 (cannot be rescheduled), counted s_waitcnt vmcnt(7)
// so next pair's 7 loads stay in flight across the current solve, and
// sched_barrier(0) after each waitcnt (rule #18: stops hipcc hoisting the
// dependent VALU above the wait). 4 pairs (8 elems) per thread; pairs are
// 80B = 5 aligned dwordx4. Math identical to R1's verified path.

#define TPB 256
#define PAIRS 4

typedef float vf4 __attribute__((ext_vector_type(4)));

struct Pair { vf4 f0, f1, f2, f3, f4, q0, q1; };

__device__ __forceinline__ void issue_loads(const float* a, const float* q,
                                            Pair& d) {
    unsigned long long aa = (unsigned long long)a;
    unsigned long long qq = (unsigned long long)q;
    asm volatile("global_load_dwordx4 %0, %1, off"           : "=v"(d.f0) : "v"(aa));
    asm volatile("global_load_dwordx4 %0, %1, off offset:16" : "=v"(d.f1) : "v"(aa));
    asm volatile("global_load_dwordx4 %0, %1, off offset:32" : "=v"(d.f2) : "v"(aa));
    asm volatile("global_load_dwordx4 %0, %1, off offset:48" : "=v"(d.f3) : "v"(aa));
    asm volatile("global_load_dwordx4 %0, %1, off offset:64" : "=v"(d.f4) : "v"(aa));
    asm volatile("global_load_dwordx4 %0, %1, off"           : "=v"(d.q0) : "v"(qq));
    asm volatile("global_load_dwordx4 %0, %1, off offset:16" : "=v"(d.q1) : "v"(qq));
}

__device__ __forceinline__ void cross4(const float* x, const float* y,
                                       const float* z, float* w) {
    float m01 = y[0]*z[1] - y[1]*z[0];
    float m02 = y[0]*z[2] - y[2]*z[0];
    float m03 = y[0]*z[3] - y[3]*z[0];
    float m12 = y[1]*z[2] - y[2]*z[1];
    float m13 = y[1]*z[3] - y[3]*z[1];
    float m23 = y[2]*z[3] - y[3]*z[2];
    w[0] =  (x[1]*m23 - x[2]*m13 + x[3]*m12);
    w[1] = -(x[0]*m23 - x[2]*m03 + x[3]*m02);
    w[2] =  (x[0]*m13 - x[1]*m03 + x[3]*m01);
    w[3] = -(x[0]*m12 - x[1]*m02 + x[2]*m01);
}

__device__ __forceinline__ float det3s(float p, float q, float r,
                                       float s, float t, float u) {
    return p*(s*u - t*t) - q*(q*u - r*t) + r*(q*t - r*s);
}

// ---- R1's proven per-element solve (identical math) ----
__device__ __forceinline__ float solve_elem(const float a[10], float4 qt) {
    float m00 = -a[0], m01 = -a[1], m02 = -a[2], m03 = -a[3];
    float m11 = -a[4], m12 = -a[5], m13 = -a[6];
    float m22 = -a[7], m23 = -a[8], m33 = -a[9];

    float e1 = m00 + m11 + m22 + m33;
    float e2 = m00*m11 - m01*m01 + m00*m22 - m02*m02 + m00*m33 - m03*m03
             + m11*m22 - m12*m12 + m11*m33 - m13*m13 + m22*m33 - m23*m23;
    float e3 = det3s(m11, m12, m13, m22, m23, m33)
             + det3s(m00, m02, m03, m22, m23, m33)
             + det3s(m00, m01, m03, m11, m13, m33)
             + det3s(m00, m01, m02, m11, m12, m22);
    float r1v[4] = {m01, m11, m12, m13};
    float r2v[4] = {m02, m12, m22, m23};
    float r3v[4] = {m03, m13, m23, m33};
    float cw[4];
    cross4(r1v, r2v, r3v, cw);
    float e4 = m00*cw[0] + m01*cw[1] + m02*cw[2] + m03*cw[3];

    float s0 = fabsf(m01) + fabsf(m02) + fabsf(m03);
    float s1 = fabsf(m01) + fabsf(m12) + fabsf(m13);
    float s2 = fabsf(m02) + fabsf(m12) + fabsf(m23);
    float s3 = fabsf(m03) + fabsf(m13) + fabsf(m23);
    float lo = fminf(fminf(m00 - s0, m11 - s1), fminf(m22 - s2, m33 - s3)) - 1e-3f;
    float hi = fminf(fminf(m00, m11), fminf(m22, m33));
    float lam = lo;
    #pragma unroll
    for (int it = 0; it < 12; ++it) {
        float p  = (((lam - e1)*lam + e2)*lam - e3)*lam + e4;
        float dp = ((4.f*lam - 3.f*e1)*lam + 2.f*e2)*lam - e3;
        dp = fminf(dp, -1e-12f);
        lam = lam - p * __builtin_amdgcn_rcpf(dp);
        lam = fminf(fmaxf(lam, lo), hi);
    }

    float R0[4] = {m00 - lam, m01, m02, m03};
    float R1[4] = {m01, m11 - lam, m12, m13};
    float R2[4] = {m02, m12, m22 - lam, m23};
    float R3[4] = {m03, m13, m23, m33 - lam};
    float c0[4], c1[4], c2[4], c3[4];
    cross4(R1, R2, R3, c0);
    cross4(R0, R2, R3, c1);
    cross4(R0, R1, R3, c2);
    cross4(R0, R1, R2, c3);
    float n0 = c0[0]*c0[0] + c0[1]*c0[1] + c0[2]*c0[2] + c0[3]*c0[3];
    float n1 = c1[0]*c1[0] + c1[1]*c1[1] + c1[2]*c1[2] + c1[3]*c1[3];
    float n2 = c2[0]*c2[0] + c2[1]*c2[1] + c2[2]*c2[2] + c2[3]*c2[3];
    float n3 = c3[0]*c3[0] + c3[1]*c3[1] + c3[2]*c3[2] + c3[3]*c3[3];

    float bn = n0, w0 = c0[0], w1 = c0[1], w2 = c0[2], w3 = c0[3];
    bool b;
    b = n1 > bn; bn = b ? n1 : bn; w0 = b ? c1[0] : w0; w1 = b ? c1[1] : w1;
                 w2 = b ? c1[2] : w2; w3 = b ? c1[3] : w3;
    b = n2 > bn; bn = b ? n2 : bn; w0 = b ? c2[0] : w0; w1 = b ? c2[1] : w1;
                 w2 = b ? c2[2] : w2; w3 = b ? c2[3] : w3;
    b = n3 > bn; bn = b ? n3 : bn; w0 = b ? c3[0] : w0; w1 = b ? c3[1] : w1;
                 w2 = b ? c3[2] : w2; w3 = b ? c3[3] : w3;

    float d = w0*qt.x + w1*qt.y + w2*qt.z + w3*qt.w;
    float inv = __builtin_amdgcn_rcpf(fmaxf(bn, 1e-20f));
    float loss = 8.f * (bn - d*d) * inv;
    return fminf(fmaxf(loss, 0.f), 8.f);
}

// DPP wave64 sum step: VALU pipe only. ctrl/mask are compile-time consts.
template <int CTRL, int ROW_MASK>
__device__ __forceinline__ float dpp_add(float v) {
    int t = __builtin_amdgcn_update_dpp(0, __builtin_bit_cast(int, v),
                                        CTRL, ROW_MASK, 0xf, true);
    return v + __builtin_bit_cast(float, t);
}

__global__ __launch_bounds__(TPB) void qcqp_loss_kernel(
    const float* __restrict__ A_vec, const float* __restrict__ q_t,
    float* __restrict__ acc, unsigned int* __restrict__ cnt,
    float* __restrict__ out, int B, int T, int nblocks)
{
    int t = blockIdx.x * blockDim.x + threadIdx.x;
    int Ptot = B >> 1;                       // whole pairs
    float lsum = 0.f;

    Pair Pd, Nd;
    // prologue: issue pair 0's loads
    int curp = t;
    {
        int c = (curp < Ptot) ? curp : 0;
        issue_loads(A_vec + (size_t)c * 20, q_t + (size_t)c * 8, Pd);
    }
    int nxtp = curp;

    #define STEP(K, VMSTR)                                                    \
    {                                                                         \
        if ((K) + 1 < PAIRS) {                                                \
            nxtp = t + ((K) + 1) * T;                                         \
            int nc = (nxtp < Ptot) ? nxtp : 0;                                \
            issue_loads(A_vec + (size_t)nc * 20, q_t + (size_t)nc * 8, Nd);   \
        }                                                                     \
        asm volatile("s_waitcnt vmcnt(" VMSTR ")" ::: "memory");              \
        __builtin_amdgcn_sched_barrier(0);                                    \
        {                                                                     \
            bool ok = (curp < Ptot);                                          \
            float a0[10] = {Pd.f0.x, Pd.f0.y, Pd.f0.z, Pd.f0.w,               \
                            Pd.f1.x, Pd.f1.y, Pd.f1.z, Pd.f1.w,               \
                            Pd.f2.x, Pd.f2.y};                                \
            float a1[10] = {Pd.f2.z, Pd.f2.w, Pd.f3.x, Pd.f3.y,               \
                            Pd.f3.z, Pd.f3.w, Pd.f4.x, Pd.f4.y,               \
                            Pd.f4.z, Pd.f4.w};                                \
            float4 qt0 = make_float4(Pd.q0.x, Pd.q0.y, Pd.q0.z, Pd.q0.w);     \
            float4 qt1 = make_float4(Pd.q1.x, Pd.q1.y, Pd.q1.z, Pd.q1.w);     \
            float L0 = solve_elem(a0, qt0);                                   \
            float L1 = solve_elem(a1, qt1);                                   \
            lsum += ok ? (L0 + L1) : 0.f;                                     \
        }                                                                     \
        Pd = Nd; curp = nxtp;                                                 \
    }

    STEP(0, "7")
    STEP(1, "7")
    STEP(2, "7")
    STEP(3, "0")
    #undef STEP

    // ---- wave64 sum on the VALU pipe (DPP), total lands in lane 63 ----
    lsum = dpp_add<0x111, 0xf>(lsum);   // row_shr:1
    lsum = dpp_add<0x112, 0xf>(lsum);   // row_shr:2
    lsum = dpp_add<0x114, 0xf>(lsum);   // row_shr:4
    lsum = dpp_add<0x118, 0xf>(lsum);   // row_shr:8
    lsum = dpp_add<0x142, 0xa>(lsum);   // row_bcast:15 -> rows 1,3
    lsum = dpp_add<0x143, 0xc>(lsum);   // row_bcast:31 -> rows 2,3
    float wsum = __builtin_bit_cast(float,
        __builtin_amdgcn_readlane(__builtin_bit_cast(int, lsum), 63));

    __shared__ float sm[TPB / 64];
    int lane = threadIdx.x & 63, wid = threadIdx.x >> 6;
    if (lane == 0) sm[wid] = wsum;
    __syncthreads();
    if (threadIdx.x == 0) {
        float bsum = sm[0] + sm[1] + sm[2] + sm[3];
        atomicAdd(acc, bsum);
        __threadfence();
        unsigned int c = atomicAdd(cnt, 1u);
        if (c == (unsigned int)(nblocks - 1)) {
            float total = atomicAdd(acc, 0.f);
            if (B & 1) {   // odd-B tail element (not hit for B=2^20)
                const float* av = A_vec + (size_t)(B - 1) * 10;
                float2 v01 = *(const float2*)(av + 0);
                float2 v23 = *(const float2*)(av + 2);
                float2 v45 = *(const float2*)(av + 4);
                float2 v67 = *(const float2*)(av + 6);
                float2 v89 = *(const float2*)(av + 8);
                float a0[10] = {v01.x, v01.y, v23.x, v23.y, v45.x,
                                v45.y, v67.x, v67.y, v89.x, v89.y};
                float4 qt0 = *(const float4*)(q_t + (size_t)(B - 1) * 4);
                total += solve_elem(a0, qt0);
            }
            out[0] = total / (float)B;
        }
    }
}

extern "C" void kernel_launch(void* const* d_in, const int* in_sizes, int n_in,
                              void* d_out, int out_size, void* d_ws, size_t ws_size,
                              hipStream_t stream)
{
    const float* A_vec = (const float*)d_in[0];
    const float* q_t   = (const float*)d_in[1];
    int B = in_sizes[0] / 10;
    float* acc = (float*)d_ws;
    unsigned int* cnt = (unsigned int*)((char*)d_ws + sizeof(float));

    (void)hipMemsetAsync(d_ws, 0, 2 * sizeof(float), stream);
    int Ptot = B >> 1;
    int nblocks = (Ptot + TPB * PAIRS - 1) / (TPB * PAIRS);
    int T = nblocks * TPB;                  // thread count; pair idx = t + k*T
    qcqp_loss_kernel<<<nblocks, TPB, 0, stream>>>(
        A_vec, q_t, acc, cnt, (float*)d_out, B, T, nblocks);
}

// Round 10
// 21.419 us; speedup vs baseline: 5.7864x; 1.6570x over previous
//
#include <hip/hip_runtime.h>

// QCQP quaternion loss. Per element: smallest eigenpair of 4x4 symmetric A
// via characteristic polynomial + monotone Newton from Gershgorin lower
// bound; eigenvector = 4D cross of 3 rows of A-lam*I (max-norm candidate);
// loss = 8(1 - <v,qt>^2/|v|^2). Mean-reduce.
//
// R9: R8's pinned-asm pipeline (proven: 48->35.5us) with two fixes:
// (a) PAIRS=2 -> 1024 blocks -> 4 waves/SIMD (R8's 512 blocks gave only 2:
//     nothing to cover the prologue latency); VGPR ~100-110 stays under the
//     128 occupancy cliff.
// (b) no memset dispatch / no atomics: block partials -> d_ws[blockIdx]
//     (every slot overwritten each call; poison-proof), tiny reduce kernel.

#define TPB 256
#define PAIRS 2

typedef float vf4 __attribute__((ext_vector_type(4)));

struct Pair { vf4 f0, f1, f2, f3, f4, q0, q1; };

__device__ __forceinline__ void issue_loads(const float* a, const float* q,
                                            Pair& d) {
    unsigned long long aa = (unsigned long long)a;
    unsigned long long qq = (unsigned long long)q;
    asm volatile("global_load_dwordx4 %0, %1, off"           : "=v"(d.f0) : "v"(aa));
    asm volatile("global_load_dwordx4 %0, %1, off offset:16" : "=v"(d.f1) : "v"(aa));
    asm volatile("global_load_dwordx4 %0, %1, off offset:32" : "=v"(d.f2) : "v"(aa));
    asm volatile("global_load_dwordx4 %0, %1, off offset:48" : "=v"(d.f3) : "v"(aa));
    asm volatile("global_load_dwordx4 %0, %1, off offset:64" : "=v"(d.f4) : "v"(aa));
    asm volatile("global_load_dwordx4 %0, %1, off"           : "=v"(d.q0) : "v"(qq));
    asm volatile("global_load_dwordx4 %0, %1, off offset:16" : "=v"(d.q1) : "v"(qq));
}

__device__ __forceinline__ void cross4(const float* x, const float* y,
                                       const float* z, float* w) {
    float m01 = y[0]*z[1] - y[1]*z[0];
    float m02 = y[0]*z[2] - y[2]*z[0];
    float m03 = y[0]*z[3] - y[3]*z[0];
    float m12 = y[1]*z[2] - y[2]*z[1];
    float m13 = y[1]*z[3] - y[3]*z[1];
    float m23 = y[2]*z[3] - y[3]*z[2];
    w[0] =  (x[1]*m23 - x[2]*m13 + x[3]*m12);
    w[1] = -(x[0]*m23 - x[2]*m03 + x[3]*m02);
    w[2] =  (x[0]*m13 - x[1]*m03 + x[3]*m01);
    w[3] = -(x[0]*m12 - x[1]*m02 + x[2]*m01);
}

__device__ __forceinline__ float det3s(float p, float q, float r,
                                       float s, float t, float u) {
    return p*(s*u - t*t) - q*(q*u - r*t) + r*(q*t - r*s);
}

// ---- R1's proven per-element solve (identical math) ----
__device__ __forceinline__ float solve_elem(const float a[10], float4 qt) {
    float m00 = -a[0], m01 = -a[1], m02 = -a[2], m03 = -a[3];
    float m11 = -a[4], m12 = -a[5], m13 = -a[6];
    float m22 = -a[7], m23 = -a[8], m33 = -a[9];

    float e1 = m00 + m11 + m22 + m33;
    float e2 = m00*m11 - m01*m01 + m00*m22 - m02*m02 + m00*m33 - m03*m03
             + m11*m22 - m12*m12 + m11*m33 - m13*m13 + m22*m33 - m23*m23;
    float e3 = det3s(m11, m12, m13, m22, m23, m33)
             + det3s(m00, m02, m03, m22, m23, m33)
             + det3s(m00, m01, m03, m11, m13, m33)
             + det3s(m00, m01, m02, m11, m12, m22);
    float r1v[4] = {m01, m11, m12, m13};
    float r2v[4] = {m02, m12, m22, m23};
    float r3v[4] = {m03, m13, m23, m33};
    float cw[4];
    cross4(r1v, r2v, r3v, cw);
    float e4 = m00*cw[0] + m01*cw[1] + m02*cw[2] + m03*cw[3];

    float s0 = fabsf(m01) + fabsf(m02) + fabsf(m03);
    float s1 = fabsf(m01) + fabsf(m12) + fabsf(m13);
    float s2 = fabsf(m02) + fabsf(m12) + fabsf(m23);
    float s3 = fabsf(m03) + fabsf(m13) + fabsf(m23);
    float lo = fminf(fminf(m00 - s0, m11 - s1), fminf(m22 - s2, m33 - s3)) - 1e-3f;
    float hi = fminf(fminf(m00, m11), fminf(m22, m33));
    float lam = lo;
    #pragma unroll
    for (int it = 0; it < 12; ++it) {
        float p  = (((lam - e1)*lam + e2)*lam - e3)*lam + e4;
        float dp = ((4.f*lam - 3.f*e1)*lam + 2.f*e2)*lam - e3;
        dp = fminf(dp, -1e-12f);
        lam = lam - p * __builtin_amdgcn_rcpf(dp);
        lam = fminf(fmaxf(lam, lo), hi);
    }

    float R0[4] = {m00 - lam, m01, m02, m03};
    float R1[4] = {m01, m11 - lam, m12, m13};
    float R2[4] = {m02, m12, m22 - lam, m23};
    float R3[4] = {m03, m13, m23, m33 - lam};
    float c0[4], c1[4], c2[4], c3[4];
    cross4(R1, R2, R3, c0);
    cross4(R0, R2, R3, c1);
    cross4(R0, R1, R3, c2);
    cross4(R0, R1, R2, c3);
    float n0 = c0[0]*c0[0] + c0[1]*c0[1] + c0[2]*c0[2] + c0[3]*c0[3];
    float n1 = c1[0]*c1[0] + c1[1]*c1[1] + c1[2]*c1[2] + c1[3]*c1[3];
    float n2 = c2[0]*c2[0] + c2[1]*c2[1] + c2[2]*c2[2] + c2[3]*c2[3];
    float n3 = c3[0]*c3[0] + c3[1]*c3[1] + c3[2]*c3[2] + c3[3]*c3[3];

    float bn = n0, w0 = c0[0], w1 = c0[1], w2 = c0[2], w3 = c0[3];
    bool b;
    b = n1 > bn; bn = b ? n1 : bn; w0 = b ? c1[0] : w0; w1 = b ? c1[1] : w1;
                 w2 = b ? c1[2] : w2; w3 = b ? c1[3] : w3;
    b = n2 > bn; bn = b ? n2 : bn; w0 = b ? c2[0] : w0; w1 = b ? c2[1] : w1;
                 w2 = b ? c2[2] : w2; w3 = b ? c2[3] : w3;
    b = n3 > bn; bn = b ? n3 : bn; w0 = b ? c3[0] : w0; w1 = b ? c3[1] : w1;
                 w2 = b ? c3[2] : w2; w3 = b ? c3[3] : w3;

    float d = w0*qt.x + w1*qt.y + w2*qt.z + w3*qt.w;
    float inv = __builtin_amdgcn_rcpf(fmaxf(bn, 1e-20f));
    float loss = 8.f * (bn - d*d) * inv;
    return fminf(fmaxf(loss, 0.f), 8.f);
}

// DPP wave64 sum step: VALU pipe only. ctrl/mask are compile-time consts.
template <int CTRL, int ROW_MASK>
__device__ __forceinline__ float dpp_add(float v) {
    int t = __builtin_amdgcn_update_dpp(0, __builtin_bit_cast(int, v),
                                        CTRL, ROW_MASK, 0xf, true);
    return v + __builtin_bit_cast(float, t);
}

__device__ __forceinline__ float wave_sum(float v) {
    v = dpp_add<0x111, 0xf>(v);   // row_shr:1
    v = dpp_add<0x112, 0xf>(v);   // row_shr:2
    v = dpp_add<0x114, 0xf>(v);   // row_shr:4
    v = dpp_add<0x118, 0xf>(v);   // row_shr:8
    v = dpp_add<0x142, 0xa>(v);   // row_bcast:15 -> rows 1,3
    v = dpp_add<0x143, 0xc>(v);   // row_bcast:31 -> rows 2,3
    return __builtin_bit_cast(float,
        __builtin_amdgcn_readlane(__builtin_bit_cast(int, v), 63));
}

__global__ __launch_bounds__(TPB) void qcqp_loss_kernel(
    const float* __restrict__ A_vec, const float* __restrict__ q_t,
    float* __restrict__ part, int B, int T)
{
    int t = blockIdx.x * blockDim.x + threadIdx.x;
    int Ptot = B >> 1;                       // whole pairs
    float lsum = 0.f;

    Pair Pd, Nd;
    int curp = t;
    {
        int c = (curp < Ptot) ? curp : 0;
        issue_loads(A_vec + (size_t)c * 20, q_t + (size_t)c * 8, Pd);
    }
    int nxtp = curp;

    #define STEP(K, VMSTR)                                                    \
    {                                                                         \
        if ((K) + 1 < PAIRS) {                                                \
            nxtp = t + ((K) + 1) * T;                                         \
            int nc = (nxtp < Ptot) ? nxtp : 0;                                \
            issue_loads(A_vec + (size_t)nc * 20, q_t + (size_t)nc * 8, Nd);   \
        }                                                                     \
        asm volatile("s_waitcnt vmcnt(" VMSTR ")" ::: "memory");              \
        __builtin_amdgcn_sched_barrier(0);                                    \
        {                                                                     \
            bool ok = (curp < Ptot);                                          \
            float a0[10] = {Pd.f0.x, Pd.f0.y, Pd.f0.z, Pd.f0.w,               \
                            Pd.f1.x, Pd.f1.y, Pd.f1.z, Pd.f1.w,               \
                            Pd.f2.x, Pd.f2.y};                                \
            float a1[10] = {Pd.f2.z, Pd.f2.w, Pd.f3.x, Pd.f3.y,               \
                            Pd.f3.z, Pd.f3.w, Pd.f4.x, Pd.f4.y,               \
                            Pd.f4.z, Pd.f4.w};                                \
            float4 qt0 = make_float4(Pd.q0.x, Pd.q0.y, Pd.q0.z, Pd.q0.w);     \
            float4 qt1 = make_float4(Pd.q1.x, Pd.q1.y, Pd.q1.z, Pd.q1.w);     \
            float L0 = solve_elem(a0, qt0);                                   \
            float L1 = solve_elem(a1, qt1);                                   \
            lsum += ok ? (L0 + L1) : 0.f;                                     \
        }                                                                     \
        Pd = Nd; curp = nxtp;                                                 \
    }

    STEP(0, "7")
    STEP(1, "0")
    #undef STEP

    float wsum = wave_sum(lsum);

    __shared__ float sm[TPB / 64];
    int lane = threadIdx.x & 63, wid = threadIdx.x >> 6;
    if (lane == 0) sm[wid] = wsum;
    __syncthreads();
    if (threadIdx.x == 0)
        part[blockIdx.x] = sm[0] + sm[1] + sm[2] + sm[3];   // plain store
}

__global__ __launch_bounds__(TPB) void qcqp_reduce_kernel(
    const float* __restrict__ part, const float* __restrict__ A_vec,
    const float* __restrict__ q_t, float* __restrict__ out,
    int nparts, int B)
{
    float s = 0.f;
    for (int i = threadIdx.x; i < nparts; i += TPB)
        s += part[i];
    float wsum = wave_sum(s);

    __shared__ float sm[TPB / 64];
    int lane = threadIdx.x & 63, wid = threadIdx.x >> 6;
    if (lane == 0) sm[wid] = wsum;
    __syncthreads();
    if (threadIdx.x == 0) {
        float total = sm[0] + sm[1] + sm[2] + sm[3];
        if (B & 1) {   // odd-B tail element (not hit for B=2^20)
            const float* av = A_vec + (size_t)(B - 1) * 10;
            float2 v01 = *(const float2*)(av + 0);
            float2 v23 = *(const float2*)(av + 2);
            float2 v45 = *(const float2*)(av + 4);
            float2 v67 = *(const float2*)(av + 6);
            float2 v89 = *(const float2*)(av + 8);
            float a0[10] = {v01.x, v01.y, v23.x, v23.y, v45.x,
                            v45.y, v67.x, v67.y, v89.x, v89.y};
            float4 qt0 = *(const float4*)(q_t + (size_t)(B - 1) * 4);
            total += solve_elem(a0, qt0);
        }
        out[0] = total / (float)B;
    }
}

extern "C" void kernel_launch(void* const* d_in, const int* in_sizes, int n_in,
                              void* d_out, int out_size, void* d_ws, size_t ws_size,
                              hipStream_t stream)
{
    const float* A_vec = (const float*)d_in[0];
    const float* q_t   = (const float*)d_in[1];
    int B = in_sizes[0] / 10;
    float* part = (float*)d_ws;

    int Ptot = B >> 1;
    int nblocks = (Ptot + TPB * PAIRS - 1) / (TPB * PAIRS);
    int T = nblocks * TPB;                  // thread count; pair idx = t + k*T
    qcqp_loss_kernel<<<nblocks, TPB, 0, stream>>>(A_vec, q_t, part, B, T);
    qcqp_reduce_kernel<<<1, TPB, 0, stream>>>(part, A_vec, q_t,
                                              (float*)d_out, nblocks, B);
}